// Round 3
// baseline (1193.021 us; speedup 1.0000x reference)
//
#include <hip/hip_runtime.h>
#include <hip/hip_bf16.h>
#include <cstdint>
#include <cstddef>

// out = x @ weight_real^T + bias
// (magnitude*cos(phase) == real, identically; weight_imag is dead.)
//
// R3: barrier-free streaming GEMM. Both MFMA operand fragments are 16B
// K-contiguous per lane, so they are loaded straight global->VGPR
// (global_load_dwordx4) with a register double-buffer prefetch. No LDS,
// no __syncthreads => compiler emits fine-grained vmcnt(N) instead of the
// vmcnt(0) barrier drain that capped the m97-style structure at ~850 TF.
// Operand reuse is served by L1/L2 (96 MB bf16 operands are L3-resident).

#define TILE 128
#define KD 4096  // compile-time K so fragment offsets fold to constants

typedef short bf16x8 __attribute__((ext_vector_type(8)));  // 8 bf16 in 4 VGPRs
typedef float f32x4 __attribute__((ext_vector_type(4)));

__device__ __forceinline__ unsigned short f2bf(float f) {
  // round-to-nearest-even fp32 -> bf16
  unsigned int x = __float_as_uint(f);
  unsigned int r = x + 0x7FFFu + ((x >> 16) & 1u);
  return (unsigned short)(r >> 16);
}

// Converts x (nA8 chunks of 8 floats) then wr (nB8 chunks) in one kernel.
__global__ void cvt_both_f32_to_bf16(const float* __restrict__ x,
                                     const float* __restrict__ wr,
                                     unsigned short* __restrict__ xa,
                                     unsigned short* __restrict__ wb,
                                     int nA8, int nB8) {
  int i = blockIdx.x * blockDim.x + threadIdx.x;
  int stride = gridDim.x * blockDim.x;
  int total = nA8 + nB8;
  for (; i < total; i += stride) {
    const float* src; unsigned short* dst; int j;
    if (i < nA8) { src = x;  dst = xa; j = i; }
    else         { src = wr; dst = wb; j = i - nA8; }
    float4 a = ((const float4*)src)[2 * j];
    float4 b = ((const float4*)src)[2 * j + 1];
    union { unsigned short u[8]; uint4 v; } o;
    o.u[0] = f2bf(a.x); o.u[1] = f2bf(a.y);
    o.u[2] = f2bf(a.z); o.u[3] = f2bf(a.w);
    o.u[4] = f2bf(b.x); o.u[5] = f2bf(b.y);
    o.u[6] = f2bf(b.z); o.u[7] = f2bf(b.w);
    ((uint4*)dst)[j] = o.v;
  }
}

// A: [M=8192, K=4096] bf16, B: [N=4096, K] bf16 (W row-major), C fp32.
// Block = 256 threads = 4 waves in 2x2; wave tile 64x64 = 4x4 MFMA 16x16x32.
// grid.x = row-blocks (so consecutive blocks share the B column band -> L2).
__global__ __launch_bounds__(256, 3)
void gemm_stream_bf16(const unsigned short* __restrict__ A,
                      const unsigned short* __restrict__ B,
                      const float* __restrict__ bias,
                      float* __restrict__ C, int M, int N) {
  const int tid = threadIdx.x;
  const int wave = tid >> 6;
  const int lane = tid & 63;
  const int lrow = lane & 15;   // fragment row (A) / col (B)
  const int quad = lane >> 4;   // k-chunk selector (0..3)
  const int mW = (wave >> 1) * 64;
  const int nW = (wave & 1) * 64;
  const int row0 = blockIdx.x * TILE;
  const int col0 = blockIdx.y * TILE;

  // Per-lane fragment base pointers (k advances by +32 elements per step).
  const unsigned short* aP = A + (size_t)(row0 + mW + lrow) * KD + quad * 8;
  const unsigned short* bP = B + (size_t)(col0 + nW + lrow) * KD + quad * 8;

  f32x4 acc[4][4];
  const f32x4 zero = {0.f, 0.f, 0.f, 0.f};
#pragma unroll
  for (int i = 0; i < 4; ++i)
#pragma unroll
    for (int j = 0; j < 4; ++j) acc[i][j] = zero;

  bf16x8 a0[4], b0[4], a1[4], b1[4];
#pragma unroll
  for (int t = 0; t < 4; ++t) {
    a0[t] = *(const bf16x8*)(aP + (size_t)t * 16 * KD);
    b0[t] = *(const bf16x8*)(bP + (size_t)t * 16 * KD);
  }

  for (int k0 = 0; k0 < KD; k0 += 64) {
    // phase A: prefetch k0+32 into buf1, compute k0 on buf0
#pragma unroll
    for (int t = 0; t < 4; ++t) {
      a1[t] = *(const bf16x8*)(aP + (size_t)t * 16 * KD + k0 + 32);
      b1[t] = *(const bf16x8*)(bP + (size_t)t * 16 * KD + k0 + 32);
    }
#pragma unroll
    for (int mt = 0; mt < 4; ++mt)
#pragma unroll
      for (int nt = 0; nt < 4; ++nt)
        acc[mt][nt] = __builtin_amdgcn_mfma_f32_16x16x32_bf16(
            a0[mt], b0[nt], acc[mt][nt], 0, 0, 0);

    // phase B: prefetch k0+64 into buf0 (guarded), compute k0+32 on buf1
    if (k0 + 64 < KD) {
#pragma unroll
      for (int t = 0; t < 4; ++t) {
        a0[t] = *(const bf16x8*)(aP + (size_t)t * 16 * KD + k0 + 64);
        b0[t] = *(const bf16x8*)(bP + (size_t)t * 16 * KD + k0 + 64);
      }
    }
#pragma unroll
    for (int mt = 0; mt < 4; ++mt)
#pragma unroll
      for (int nt = 0; nt < 4; ++nt)
        acc[mt][nt] = __builtin_amdgcn_mfma_f32_16x16x32_bf16(
            a1[mt], b1[nt], acc[mt][nt], 0, 0, 0);
  }

  // Epilogue: D[row = quad*4 + r][col = lrow] per 16x16 tile; add bias.
#pragma unroll
  for (int nt = 0; nt < 4; ++nt) {
    int col = col0 + nW + nt * 16 + lrow;
    float bv = bias[col];
#pragma unroll
    for (int mt = 0; mt < 4; ++mt) {
      int rowb = row0 + mW + mt * 16 + quad * 4;
#pragma unroll
      for (int r = 0; r < 4; ++r) {
        C[(size_t)(rowb + r) * N + col] = acc[mt][nt][r] + bv;
      }
    }
  }
}

// Fallback (ws too small): proven R1 structure — fp32 loads, in-register
// convert, ds_write staging, BK=32, 2-barrier K-loop.
#define BKF 32
__global__ void gemm_bt_f32in(const float* __restrict__ Afp,
                              const float* __restrict__ Bfp,
                              const float* __restrict__ bias,
                              float* __restrict__ C,
                              int M, int N, int K) {
  __shared__ unsigned short Als[TILE * BKF];
  __shared__ unsigned short Bls[TILE * BKF];
  const int tid = threadIdx.x;
  const int wave = tid >> 6;
  const int lane = tid & 63;
  const int lrow = lane & 15;
  const int quad = lane >> 4;
  const int mW = (wave >> 1) * 64;
  const int nW = (wave & 1) * 64;
  const int row0 = blockIdx.y * TILE;
  const int col0 = blockIdx.x * TILE;

  f32x4 acc[4][4];
  const f32x4 zero = {0.f, 0.f, 0.f, 0.f};
#pragma unroll
  for (int i = 0; i < 4; ++i)
#pragma unroll
    for (int j = 0; j < 4; ++j) acc[i][j] = zero;

  for (int k0 = 0; k0 < K; k0 += BKF) {
#pragma unroll
    for (int c = 0; c < 2; ++c) {
      int e0 = c * 2048 + tid * 8;
      int r = e0 >> 5;
      int kc = e0 & 31;
      const float* ga = Afp + (size_t)(row0 + r) * K + k0 + kc;
      const float* gb = Bfp + (size_t)(col0 + r) * K + k0 + kc;
      float4 af0 = ((const float4*)ga)[0];
      float4 af1 = ((const float4*)ga)[1];
      float4 bf0 = ((const float4*)gb)[0];
      float4 bf1 = ((const float4*)gb)[1];
      union { unsigned short u[8]; uint4 v; } oa, ob;
      oa.u[0] = f2bf(af0.x); oa.u[1] = f2bf(af0.y);
      oa.u[2] = f2bf(af0.z); oa.u[3] = f2bf(af0.w);
      oa.u[4] = f2bf(af1.x); oa.u[5] = f2bf(af1.y);
      oa.u[6] = f2bf(af1.z); oa.u[7] = f2bf(af1.w);
      ob.u[0] = f2bf(bf0.x); ob.u[1] = f2bf(bf0.y);
      ob.u[2] = f2bf(bf0.z); ob.u[3] = f2bf(bf0.w);
      ob.u[4] = f2bf(bf1.x); ob.u[5] = f2bf(bf1.y);
      ob.u[6] = f2bf(bf1.z); ob.u[7] = f2bf(bf1.w);
      *(uint4*)&Als[e0] = oa.v;
      *(uint4*)&Bls[e0] = ob.v;
    }
    __syncthreads();
    bf16x8 af[4], bfr[4];
#pragma unroll
    for (int t = 0; t < 4; ++t) {
      af[t]  = *(const bf16x8*)&Als[(mW + t * 16 + lrow) * BKF + quad * 8];
      bfr[t] = *(const bf16x8*)&Bls[(nW + t * 16 + lrow) * BKF + quad * 8];
    }
#pragma unroll
    for (int mt = 0; mt < 4; ++mt)
#pragma unroll
      for (int nt = 0; nt < 4; ++nt)
        acc[mt][nt] = __builtin_amdgcn_mfma_f32_16x16x32_bf16(
            af[mt], bfr[nt], acc[mt][nt], 0, 0, 0);
    __syncthreads();
  }
#pragma unroll
  for (int nt = 0; nt < 4; ++nt) {
    int col = col0 + nW + nt * 16 + lrow;
    float bv = bias[col];
#pragma unroll
    for (int mt = 0; mt < 4; ++mt) {
      int rowb = row0 + mW + mt * 16 + quad * 4;
#pragma unroll
      for (int r = 0; r < 4; ++r) {
        C[(size_t)(rowb + r) * N + col] = acc[mt][nt][r] + bv;
      }
    }
  }
}

extern "C" void kernel_launch(void* const* d_in, const int* in_sizes, int n_in,
                              void* d_out, int out_size, void* d_ws, size_t ws_size,
                              hipStream_t stream) {
  const int M = 8192, N = 4096, K = 4096;
  const float* x = (const float*)d_in[0];
  const float* wr = (const float*)d_in[1];
  // d_in[2] (weight_imag) is provably unused: mag*cos(phase) == real.
  const float* bias = (const float*)d_in[3];
  float* out = (float*)d_out;

  const size_t nA = (size_t)M * K;
  const size_t nB = (size_t)N * K;

  if (ws_size >= (nA + nB) * sizeof(unsigned short)) {
    unsigned short* xa = (unsigned short*)d_ws;
    unsigned short* wb = xa + nA;
    hipLaunchKernelGGL(cvt_both_f32_to_bf16, dim3(4096), dim3(256), 0, stream,
                       x, wr, xa, wb, (int)(nA / 8), (int)(nB / 8));
    dim3 grid(M / TILE, N / TILE);  // x = rows: neighbors share B band in L2
    hipLaunchKernelGGL(gemm_stream_bf16, grid, dim3(256), 0, stream,
                       xa, wb, bias, out, M, N);
  } else {
    dim3 grid(N / TILE, M / TILE);
    hipLaunchKernelGGL(gemm_bt_f32in, grid, dim3(256), 0, stream,
                       x, wr, bias, out, M, N, K);
  }
}